// Round 17
// baseline (2208.335 us; speedup 1.0000x reference)
//
#include <hip/hip_runtime.h>

// EGNN layer: N=50000 nodes, E=800000 edges, H=256.
// Round 17: col-sorted processing order within each row-chunk. R16 falsified
// stream-eviction (NT hints neutral); the 160MB/chunk FETCH (vs 49MB unique
// P2 rows) is order-driven intra-chunk re-fetch of the random P2 gather.
// Counting-sort edges by col within each chunk (sperm[q]=le): P2 reads become
// sequential (fetched once), random side moves to P1 (12.6MB/chunk, L3-easy).
// mBuf/att/cw still written at row-CSR slot le -> node_agg unchanged.

#define NN 50000
#define EE 800000

typedef unsigned short u16;
typedef float f32x4 __attribute__((ext_vector_type(4)));
typedef short bf16x8 __attribute__((ext_vector_type(8)));
typedef unsigned uint4v __attribute__((ext_vector_type(4)));

__device__ __forceinline__ u16 f2bf(float f) {
  unsigned u = __float_as_uint(f);
  u = (u + 0x7FFFu + ((u >> 16) & 1u)) >> 16;
  return (u16)u;
}
__device__ __forceinline__ float bf2f(u16 s) {
  return __uint_as_float(((unsigned)s) << 16);
}
__device__ __forceinline__ float bflo(unsigned u) { return __uint_as_float(u << 16); }
__device__ __forceinline__ float bfhi(unsigned u) { return __uint_as_float(u & 0xFFFF0000u); }
__device__ __forceinline__ float silu_f(float x) {
  return x * __builtin_amdgcn_rcpf(1.f + exp2f(x * -1.44269504f));
}

__device__ __forceinline__ void gload16(const void* g, void* l) {
  __builtin_amdgcn_global_load_lds(
      (const __attribute__((address_space(1))) void*)g,
      (__attribute__((address_space(3))) void*)l, 16, 0, 0);
}

// ---------------- fused edge kernel (BM=64, col-sorted order) ----------------
__global__ __launch_bounds__(256, 2) void edge_fused(
    const u16* __restrict__ P1, const u16* __restrict__ P2,
    const float* __restrict__ dist, const float* __restrict__ eattr,
    const float* __restrict__ Wt, const float* __restrict__ ge,
    const float* __restrict__ beln, const float* __restrict__ be2,
    const float* __restrict__ bc1, const float* __restrict__ Wa,
    const float* __restrict__ ba, const float* __restrict__ Wc2,
    const u16* __restrict__ We2f, const u16* __restrict__ Wc1f,
    const int* __restrict__ rowp, const int* __restrict__ colp,
    const int* __restrict__ perm, const int* __restrict__ sperm,
    const int* __restrict__ meta, int cidx,
    u16* __restrict__ mBuf, float* __restrict__ att, float* __restrict__ cwv) {
  const int M = meta[2 * cidx + 1];
  const int eb = meta[2 * cidx];
  const int m0 = blockIdx.x * 64;
  if (m0 >= M) return;
  __shared__ __align__(16) u16 At[64][512];     // 64 KB; P3: Mt rows 0..31, red row 32
  __shared__ int sle[64];
  const int tid = threadIdx.x, w = tid >> 6, lane = tid & 63;
  const int l15 = lane & 15, kq = lane >> 4;
  const int ch0 = lane * 8;

  if (tid < 64) {
    int sq = m0 + tid; if (sq > M - 1) sq = M - 1;
    sle[tid] = sperm[eb + sq];
  }
  __syncthreads();

  // ---- phase 1: eadd (metadata pre-staged lane-parallel) ----
  {
    const int le0 = sle[w * 16 + (lane & 15)];
    const int e_l = perm[eb + le0];
    const int r_l = rowp[e_l];
    const int c_l = colp[e_l];
    const float dd_l = dist[e_l];

    float wreg[8][15], gg[8], bb[8];
#pragma unroll
    for (int i = 0; i < 8; i++) {
#pragma unroll
      for (int j = 0; j < 15; j++) wreg[i][j] = Wt[(ch0 + i) * 16 + j];
      gg[i] = ge[ch0 + i]; bb[i] = beln[ch0 + i];
    }
#pragma unroll 2
    for (int rr = 0; rr < 16; rr++) {
      int e = __shfl(e_l, rr);
      int r = __shfl(r_l, rr);
      int c = __shfl(c_l, rr);
      float dd = __shfl(dd_l, rr);
      float fa[13];
#pragma unroll
      for (int j = 0; j < 13; j++) fa[j] = eattr[(size_t)e * 13 + j];
      uint4v u1 = *(const uint4v*)&P1[(size_t)r * 512 + ch0];
      uint4v u2 = *(const uint4v*)&P2[(size_t)c * 512 + ch0];
      float sv[8], s1 = 0.f, s2 = 0.f;
#pragma unroll
      for (int i = 0; i < 8; i++) {
        float xp = (i & 1) ? bfhi(u1[i >> 1]) : bflo(u1[i >> 1]);
        float xq = (i & 1) ? bfhi(u2[i >> 1]) : bflo(u2[i >> 1]);
        float x = xp + xq + wreg[i][0] + dd * wreg[i][1];
#pragma unroll
        for (int j = 0; j < 13; j++) x = fmaf(fa[j], wreg[i][2 + j], x);
        float s = silu_f(x);
        sv[i] = s; s1 += s; s2 += s * s;
      }
#pragma unroll
      for (int o = 32; o; o >>= 1) { s1 += __shfl_xor(s1, o); s2 += __shfl_xor(s2, o); }
      float mu = s1 * (1.f / 512.f);
      float inv = rsqrtf(s2 * (1.f / 512.f) - mu * mu + 1e-5f);
      int row = w * 16 + rr;
      u16 ot[8];
#pragma unroll
      for (int i = 0; i < 8; i++) ot[i] = f2bf((sv[i] - mu) * inv * gg[i] + bb[i]);
      *(uint4v*)&At[row][(lane ^ (row & 7)) * 8] = *(const uint4v*)ot;
    }
  }
  __syncthreads();

  // ---- phase 2: m-GEMM K=512, barrier-free ----
  f32x4 acc[4][4] = {};
  {
    const u16* Bw = We2f + (size_t)w * 32768;   // 16 ks x 4 j x 64 lanes x 8
    __builtin_amdgcn_s_setprio(1);
#pragma unroll 4
    for (int ks = 0; ks < 16; ks++) {
      bf16x8 bfr[4], af[4];
#pragma unroll
      for (int j = 0; j < 4; j++)
        bfr[j] = *(const bf16x8*)&Bw[((ks * 4 + j) * 64 + lane) * 8];
#pragma unroll
      for (int i = 0; i < 4; i++) {
        int rw = i * 16 + l15;
        af[i] = *(const bf16x8*)&At[rw][((ks * 4 + kq) ^ (rw & 7)) * 8];
      }
#pragma unroll
      for (int i = 0; i < 4; i++)
#pragma unroll
        for (int j = 0; j < 4; j++)
          acc[i][j] = __builtin_amdgcn_mfma_f32_16x16x32_bf16(af[i], bfr[j], acc[i][j], 0, 0, 0);
    }
    __builtin_amdgcn_s_setprio(0);
  }
  __syncthreads();   // all At reads done before Mt overwrite

  // ---- m epilogue: mBuf (at sle[row]) + Mt(LDS) + att partials ----
  u16* Mt = &At[0][0];                  // [64][256] swizzled = At rows 0..31
  float* red = (float*)&At[32][0];      // [64][4]
  float ds_a[4][4];
#pragma unroll
  for (int i = 0; i < 4; i++)
#pragma unroll
    for (int t = 0; t < 4; t++) ds_a[i][t] = 0.f;
#pragma unroll
  for (int j = 0; j < 4; j++) {
    int col = w * 64 + j * 16 + l15;
    float bz = be2[col], wa = Wa[col];
    int slot = col >> 3, offc = col & 7;
#pragma unroll
    for (int i = 0; i < 4; i++) {
#pragma unroll
      for (int t = 0; t < 4; t++) {
        int row = i * 16 + kq * 4 + t;
        float sv = silu_f(acc[i][j][t] + bz);
        if (m0 + row < M)
          mBuf[(size_t)sle[row] * 256 + col] = f2bf(sv);
        Mt[row * 256 + ((slot ^ (row & 7)) << 3) + offc] = f2bf(sv);
        ds_a[i][t] += sv * wa;
      }
    }
  }
#pragma unroll
  for (int i = 0; i < 4; i++)
#pragma unroll
    for (int t = 0; t < 4; t++) {
      float s = ds_a[i][t];
      s += __shfl_xor(s, 1); s += __shfl_xor(s, 2);
      s += __shfl_xor(s, 4); s += __shfl_xor(s, 8);
      if (l15 == 0) red[(i * 16 + kq * 4 + t) * 4 + w] = s;
    }
  __syncthreads();
  if (tid < 64) {
    if (m0 + tid < M) {
      float s = red[tid * 4] + red[tid * 4 + 1] + red[tid * 4 + 2] + red[tid * 4 + 3] + ba[0];
      att[sle[tid]] = __builtin_amdgcn_rcpf(1.f + exp2f(s * -1.44269504f));
    }
  }

  // ---- phase 3: c1-GEMM K=256 over Mt, barrier-free ----
  f32x4 ac2[4][4] = {};
  {
    const u16* Bw = Wc1f + (size_t)w * 16384;   // 8 ks x 4 j x 64 lanes x 8
    __builtin_amdgcn_s_setprio(1);
#pragma unroll 4
    for (int ks = 0; ks < 8; ks++) {
      bf16x8 bfr[4], af[4];
#pragma unroll
      for (int j = 0; j < 4; j++)
        bfr[j] = *(const bf16x8*)&Bw[((ks * 4 + j) * 64 + lane) * 8];
#pragma unroll
      for (int i = 0; i < 4; i++) {
        int rw = i * 16 + l15;
        af[i] = *(const bf16x8*)&Mt[rw * 256 + (((ks * 4 + kq) ^ (rw & 7)) << 3)];
      }
#pragma unroll
      for (int i = 0; i < 4; i++)
#pragma unroll
        for (int j = 0; j < 4; j++)
          ac2[i][j] = __builtin_amdgcn_mfma_f32_16x16x32_bf16(af[i], bfr[j], ac2[i][j], 0, 0, 0);
    }
    __builtin_amdgcn_s_setprio(0);
  }
  float ds_c[4][4];
#pragma unroll
  for (int i = 0; i < 4; i++)
#pragma unroll
    for (int t = 0; t < 4; t++) ds_c[i][t] = 0.f;
#pragma unroll
  for (int j = 0; j < 4; j++) {
    int col = w * 64 + j * 16 + l15;
    float bz = bc1[col], wc = Wc2[col];
#pragma unroll
    for (int i = 0; i < 4; i++)
#pragma unroll
      for (int t = 0; t < 4; t++)
        ds_c[i][t] += silu_f(ac2[i][j][t] + bz) * wc;
  }
  __syncthreads();   // red reads (att) done before overwrite
#pragma unroll
  for (int i = 0; i < 4; i++)
#pragma unroll
    for (int t = 0; t < 4; t++) {
      float s = ds_c[i][t];
      s += __shfl_xor(s, 1); s += __shfl_xor(s, 2);
      s += __shfl_xor(s, 4); s += __shfl_xor(s, 8);
      if (l15 == 0) red[(i * 16 + kq * 4 + t) * 4 + w] = s;
    }
  __syncthreads();
  if (tid < 64) {
    if (m0 + tid < M)
      cwv[sle[tid]] = red[tid * 4] + red[tid * 4 + 1] + red[tid * 4 + 2] + red[tid * 4 + 3];
  }
}

// ---------------- 128x128 MFMA GEMM (node/feedback paths) --------------------
template <int MODE, int GATHER>
__global__ __launch_bounds__(256) void gemm128(
    const u16* __restrict__ A, const u16* __restrict__ BT,
    const float* __restrict__ bias, void* __restrict__ outp,
    int Mh, int Nc, int K,
    const u16* __restrict__ hbf, const u16* __restrict__ src2,
    const float* __restrict__ cnt, const float* __restrict__ b2, float scale) {
  const int M = Mh;
  const int m0 = blockIdx.x * 128, n0 = blockIdx.y * 128;
  if (m0 >= M) return;
  __shared__ __align__(16) u16 As[128][32];
  __shared__ __align__(16) u16 Bs[128][32];
  const int tid = threadIdx.x, w = tid >> 6, lane = tid & 63;
  const int srow = lane >> 2, sch = (lane & 3) * 8;
  const int r0 = w * 32 + srow, r1 = r0 + 16;

  u16* as0 = &As[w * 32][0];
  u16* as1 = &As[w * 32 + 16][0];
  u16* bs0 = &Bs[w * 32][0];
  u16* bs1 = &Bs[w * 32 + 16][0];

  const u16 *a0r, *a0c, *a1r, *a1c;
  a0c = a1c = nullptr;
  if (GATHER == 2) {
    int q0 = m0 + r0; if (q0 > M - 1) q0 = M - 1;
    int q1 = m0 + r1; if (q1 > M - 1) q1 = M - 1;
    a0r = hbf + (size_t)q0 * 256;  a0c = src2 + (size_t)q0 * 256;
    a1r = hbf + (size_t)q1 * 256;  a1c = src2 + (size_t)q1 * 256;
  } else {
    a0r = A + (size_t)(m0 + r0) * K;
    a1r = A + (size_t)(m0 + r1) * K;
  }
  const u16* b0 = BT + (size_t)(n0 + r0) * K;
  const u16* b1 = BT + (size_t)(n0 + r1) * K;

  f32x4 acc[4][4] = {};
  const int l15 = lane & 15, ko = (lane >> 4) * 8;
  const int ar0 = (w >> 1) * 64, br0 = (w & 1) * 64;

  for (int k0 = 0; k0 < K; k0 += 32) {
    const u16 *pa0, *pa1;
    if (GATHER == 2) {
      if (k0 < 256) { pa0 = a0r + k0;         pa1 = a1r + k0; }
      else          { pa0 = a0c + (k0 - 256); pa1 = a1c + (k0 - 256); }
    } else { pa0 = a0r + k0; pa1 = a1r + k0; }
    gload16(pa0 + sch, as0);
    gload16(pa1 + sch, as1);
    gload16(b0 + k0 + sch, bs0);
    gload16(b1 + k0 + sch, bs1);
    __syncthreads();
    bf16x8 af[4], bfr[4];
#pragma unroll
    for (int i = 0; i < 4; i++)
      af[i] = *reinterpret_cast<const bf16x8*>(&As[ar0 + i * 16 + l15][ko]);
#pragma unroll
    for (int j = 0; j < 4; j++)
      bfr[j] = *reinterpret_cast<const bf16x8*>(&Bs[br0 + j * 16 + l15][ko]);
#pragma unroll
    for (int i = 0; i < 4; i++)
#pragma unroll
      for (int j = 0; j < 4; j++)
        acc[i][j] = __builtin_amdgcn_mfma_f32_16x16x32_bf16(af[i], bfr[j], acc[i][j], 0, 0, 0);
    __syncthreads();
  }

  const int rb = m0 + ar0 + ((lane >> 4) << 2);
#pragma unroll
  for (int j = 0; j < 4; j++) {
    const int gc = n0 + br0 + j * 16 + l15;
    const float bz = (MODE == 2 || MODE == 7) ? 0.f : bias[gc];
#pragma unroll
    for (int i = 0; i < 4; i++) {
#pragma unroll
      for (int t = 0; t < 4; t++) {
        const int gr = rb + i * 16 + t;
        if (gr >= M) continue;
        float v = acc[i][j][t] + bz;
        size_t oi = (size_t)gr * Nc + gc;
        if (MODE == 0)      ((u16*)outp)[oi] = f2bf(silu_f(v));
        else if (MODE == 1) ((float*)outp)[oi] = v;
        else if (MODE == 2) ((float*)outp)[oi] += scale * (v + cnt[gr] * b2[gc]);
        else if (MODE == 7) ((u16*)outp)[oi] = f2bf(v);
      }
    }
  }
}

// ---------------- weight transpose + bf16: src[K,N] -> dst[N,Kpad] -----------
__global__ void wtrans(const float* __restrict__ src, u16* __restrict__ dst,
                       int K, int Nn, int Kpad) {
  int t = blockIdx.x * 256 + threadIdx.x;
  if (t >= Nn * Kpad) return;
  int n = t / Kpad, k = t - n * Kpad;
  float v = (k < K) ? src[(size_t)k * Nn + n] : 0.f;
  dst[t] = f2bf(v);
}

// fragment-ordered B for barrier-free fused GEMMs
__global__ void build_wf(const float* __restrict__ src, u16* __restrict__ dst,
                         int K, int Nn) {
  int t = blockIdx.x * 256 + threadIdx.x;
  if (t >= Nn * K) return;
  int i = t & 7;
  int lane = (t >> 3) & 63;
  int rest = t >> 9;
  int j = rest & 3;
  int rest2 = rest >> 2;
  int KS = K >> 5;
  int wv = rest2 / KS, ks = rest2 - wv * KS;
  int n = wv * 64 + j * 16 + (lane & 15);
  int k = ks * 32 + (lane >> 4) * 8 + i;
  dst[t] = f2bf(src[(size_t)k * Nn + n]);
}

// Wt[n][16] = {b_e1[n], W_e1[512][n], W_e1[513..525][n], 0}
__global__ void build_wt(const float* __restrict__ W_e1, const float* __restrict__ b_e1,
                         float* __restrict__ Wt) {
  int t = blockIdx.x * 256 + threadIdx.x;
  if (t >= 512 * 16) return;
  int n = t >> 4, j = t & 15;
  float v = 0.f;
  if (j == 0) v = b_e1[n];
  else if (j < 15) v = W_e1[(size_t)(511 + j) * 512 + n];
  Wt[t] = v;
}

__global__ void edge_geom(const float* __restrict__ pos, const int* __restrict__ row,
                          const int* __restrict__ colx, float* __restrict__ dist,
                          int* __restrict__ icnt) {
  int e = blockIdx.x * 256 + threadIdx.x;
  if (e >= EE) return;
  int r = row[e], c = colx[e];
  float d0 = pos[r * 3 + 0] - pos[c * 3 + 0];
  float d1 = pos[r * 3 + 1] - pos[c * 3 + 1];
  float d2 = pos[r * 3 + 2] - pos[c * 3 + 2];
  dist[e] = fmaxf(sqrtf(d0 * d0 + d1 * d1 + d2 * d2), 1e-5f);
  atomicAdd(&icnt[r], 1);
}

__global__ __launch_bounds__(1024) void scan_ptr(const int* __restrict__ icnt,
                                                 int* __restrict__ ptr) {
  __shared__ int ls[1024];
  const int t = threadIdx.x;
  const int SEG = (NN + 1023) / 1024;
  int s0 = t * SEG;
  int s1 = s0 + SEG; if (s1 > NN) s1 = NN;
  int sum = 0;
  for (int i = s0; i < s1; i++) sum += icnt[i];
  ls[t] = sum;
  __syncthreads();
  for (int off = 1; off < 1024; off <<= 1) {
    int v = (t >= off) ? ls[t - off] : 0;
    __syncthreads();
    ls[t] += v;
    __syncthreads();
  }
  int run = ls[t] - sum;
  for (int i = s0; i < s1; i++) { ptr[i] = run; run += icnt[i]; }
  if (t == 1023) ptr[NN] = ls[1023];
}

__global__ void copy_head(const int* __restrict__ ptr, int* __restrict__ head,
                          float* __restrict__ cntf) {
  int n = blockIdx.x * 256 + threadIdx.x;
  if (n >= NN) return;
  head[n] = ptr[n];
  cntf[n] = (float)(ptr[n + 1] - ptr[n]);
}

__global__ void fill_perm(const int* __restrict__ row, int* __restrict__ head,
                          int* __restrict__ perm) {
  int e = blockIdx.x * 256 + threadIdx.x;
  if (e >= EE) return;
  int p = atomicAdd(&head[row[e]], 1);
  perm[p] = e;
}

__global__ void chunk_meta(const int* __restrict__ ptr, int* __restrict__ meta,
                           int CN, int nch, int capE) {
  int c = blockIdx.x * 256 + threadIdx.x;
  if (c >= nch) return;
  int lo = c * CN;
  int hi = lo + CN; if (hi > NN) hi = NN;
  int b = ptr[lo];
  int cc = ptr[hi] - b;
  if (cc > capE) cc = capE;
  meta[2 * c + 0] = b;
  meta[2 * c + 1] = cc;
}

// ---------------- per-chunk col counting sort ---------------------------------
__global__ void chist(const int* __restrict__ colp, const int* __restrict__ perm,
                      const int* __restrict__ meta, int nch, int* __restrict__ hist) {
  int p = blockIdx.x * 256 + threadIdx.x;
  if (p >= EE) return;
  int c = nch - 1;
  while (c > 0 && p < meta[2 * c]) c--;
  atomicAdd(&hist[(size_t)c * NN + colp[perm[p]]], 1);
}

__global__ __launch_bounds__(1024) void cscan(int* __restrict__ data) {
  int c = blockIdx.x;
  int* d = data + (size_t)c * NN;
  __shared__ int ls[1024];
  const int t = threadIdx.x;
  const int SEG = (NN + 1023) / 1024;
  int s0 = t * SEG;
  int s1 = s0 + SEG; if (s1 > NN) s1 = NN;
  int sum = 0;
  for (int i = s0; i < s1; i++) sum += d[i];
  ls[t] = sum;
  __syncthreads();
  for (int off = 1; off < 1024; off <<= 1) {
    int v = (t >= off) ? ls[t - off] : 0;
    __syncthreads();
    ls[t] += v;
    __syncthreads();
  }
  int run = ls[t] - sum;
  for (int i = s0; i < s1; i++) { int cc = d[i]; d[i] = run; run += cc; }
}

__global__ void cscatter(const int* __restrict__ colp, const int* __restrict__ perm,
                         const int* __restrict__ meta, int nch,
                         int* __restrict__ chead, int* __restrict__ sperm) {
  int p = blockIdx.x * 256 + threadIdx.x;
  if (p >= EE) return;
  int c = nch - 1;
  while (c > 0 && p < meta[2 * c]) c--;
  int b = meta[2 * c];
  int q = atomicAdd(&chead[(size_t)c * NN + colp[perm[p]]], 1);
  sperm[b + q] = p - b;
}

// ---------------- in-place row LayerNorm on bf16, D=512 (node phase) ---------
__global__ __launch_bounds__(128) void ln_512(u16* __restrict__ t,
                                              const float* __restrict__ g,
                                              const float* __restrict__ b, int Mh) {
  int row = blockIdx.x;
  if (row >= Mh) return;
  int tid = threadIdx.x;
  size_t base = (size_t)row * 512 + tid * 4;
  ushort4 xv = *reinterpret_cast<const ushort4*>(&t[base]);
  float x0 = bf2f(xv.x), x1 = bf2f(xv.y), x2 = bf2f(xv.z), x3 = bf2f(xv.w);
  float s1 = x0 + x1 + x2 + x3;
  float s2 = x0 * x0 + x1 * x1 + x2 * x2 + x3 * x3;
  for (int o = 32; o; o >>= 1) { s1 += __shfl_xor(s1, o); s2 += __shfl_xor(s2, o); }
  __shared__ float red[4];
  if ((tid & 63) == 0) { red[tid >> 6] = s1; red[2 + (tid >> 6)] = s2; }
  __syncthreads();
  s1 = red[0] + red[1]; s2 = red[2] + red[3];
  float mu = s1 * (1.f / 512.f);
  float var = s2 * (1.f / 512.f) - mu * mu;
  float inv = rsqrtf(var + 1e-5f);
  int c = tid * 4;
  ushort4 yv;
  yv.x = f2bf((x0 - mu) * inv * g[c + 0] + b[c + 0]);
  yv.y = f2bf((x1 - mu) * inv * g[c + 1] + b[c + 1]);
  yv.z = f2bf((x2 - mu) * inv * g[c + 2] + b[c + 2]);
  yv.w = f2bf((x3 - mu) * inv * g[c + 3] + b[c + 3]);
  *reinterpret_cast<ushort4*>(&t[base]) = yv;
}

// ---------------- per-node aggregation -----------------------------------------
__global__ __launch_bounds__(256) void node_agg(
    const u16* __restrict__ m, const float* __restrict__ att,
    const float* __restrict__ cwv,
    const float* __restrict__ pos, const int* __restrict__ colx,
    const int* __restrict__ perm, const int* __restrict__ ptr,
    const int* __restrict__ meta, int cidx,
    u16* __restrict__ aggbf, float* __restrict__ cagg, int nlo, int cn) {
  int w = threadIdx.x >> 6, lane = threadIdx.x & 63;
  int nl = blockIdx.x * 4 + w;
  if (nl >= cn) return;
  int n = nlo + nl;
  int base = meta[2 * cidx];
  int p0 = ptr[n], p1 = ptr[n + 1];
  const int half = lane >> 5, ch = (lane & 31) * 8;
  float a[8] = {};
  for (int p = p0 + half; p < p1; p += 2) {
    int le = p - base;
    float at = att[le];
    uint4v mv = *reinterpret_cast<const uint4v*>(&m[(size_t)le * 256 + ch]);
#pragma unroll
    for (int i = 0; i < 4; i++) {
      a[2 * i]     += at * bflo(mv[i]);
      a[2 * i + 1] += at * bfhi(mv[i]);
    }
  }
#pragma unroll
  for (int i = 0; i < 8; i++) a[i] += __shfl_xor(a[i], 32);
  if (half == 0) {
    u16 ot[8];
#pragma unroll
    for (int i = 0; i < 8; i++) ot[i] = f2bf(a[i]);
    *reinterpret_cast<uint4v*>(&aggbf[(size_t)n * 256 + ch]) =
        *reinterpret_cast<const uint4v*>(ot);
  }
  float prx = pos[n * 3 + 0], pry = pos[n * 3 + 1], prz = pos[n * 3 + 2];
  float sx = 0.f, sy = 0.f, sz = 0.f;
  for (int p = p0 + lane; p < p1; p += 64) {
    int le = p - base;
    float cv = cwv[le];
    int c = colx[perm[p]];
    sx += cv * (prx - pos[c * 3 + 0]);
    sy += cv * (pry - pos[c * 3 + 1]);
    sz += cv * (prz - pos[c * 3 + 2]);
  }
#pragma unroll
  for (int o = 32; o; o >>= 1) {
    sx += __shfl_xor(sx, o); sy += __shfl_xor(sy, o); sz += __shfl_xor(sz, o);
  }
  if (lane == 0) {
    cagg[n * 3 + 0] = sx; cagg[n * 3 + 1] = sy; cagg[n * 3 + 2] = sz;
  }
}

__global__ __launch_bounds__(64) void hmid_ln(const float* __restrict__ h,
                                              const float* __restrict__ hupd,
                                              const float* __restrict__ g,
                                              const float* __restrict__ b,
                                              float* __restrict__ outp) {
  int row = blockIdx.x, lane = threadIdx.x;
  size_t base = (size_t)row * 256 + lane * 4;
  float x[4];
#pragma unroll
  for (int i = 0; i < 4; i++) x[i] = h[base + i] + hupd[base + i];
  float s1 = x[0] + x[1] + x[2] + x[3];
  float s2 = x[0] * x[0] + x[1] * x[1] + x[2] * x[2] + x[3] * x[3];
  for (int o = 32; o; o >>= 1) { s1 += __shfl_xor(s1, o); s2 += __shfl_xor(s2, o); }
  float mu = s1 * (1.f / 256.f);
  float var = s2 * (1.f / 256.f) - mu * mu;
  float inv = rsqrtf(var + 1e-5f);
#pragma unroll
  for (int i = 0; i < 4; i++)
    outp[base + i] = (x[i] - mu) * inv * g[lane * 4 + i] + b[lane * 4 + i];
}

__global__ void posnew_k(const float* __restrict__ pos, const float* __restrict__ cagg,
                         float* __restrict__ op) {
  int t = blockIdx.x * 256 + threadIdx.x;
  if (t >= NN * 3) return;
  op[t] = pos[t] + cagg[t];
}

__global__ void dnn_k(const float* __restrict__ posn, const int* __restrict__ rowp,
                      const int* __restrict__ colp, const int* __restrict__ perm,
                      float* __restrict__ dnc) {
  int p = blockIdx.x * 256 + threadIdx.x;
  if (p >= EE) return;
  int e = perm[p];
  int r = rowp[e], c = colp[e];
  float d0 = posn[r * 3 + 0] - posn[c * 3 + 0];
  float d1 = posn[r * 3 + 1] - posn[c * 3 + 1];
  float d2 = posn[r * 3 + 2] - posn[c * 3 + 2];
  dnc[p] = fmaxf(sqrtf(d0 * d0 + d1 * d1 + d2 * d2), 1e-5f);
}

__global__ __launch_bounds__(256) void edge_fb2(
    const float* __restrict__ dnc, const int* __restrict__ ptr,
    const float* __restrict__ Wf1, const float* __restrict__ bf1,
    u16* __restrict__ Sbf) {
  int w = threadIdx.x >> 6, lane = threadIdx.x & 63;
  int n = blockIdx.x * 4 + w;
  if (n >= NN) return;
  const float L2E = 1.44269504f;
  float w0 = Wf1[lane * 4 + 0], w1 = Wf1[lane * 4 + 1];
  float w2 = Wf1[lane * 4 + 2], w3 = Wf1[lane * 4 + 3];
  float b0 = bf1[lane * 4 + 0], b1 = bf1[lane * 4 + 1];
  float b2 = bf1[lane * 4 + 2], b3 = bf1[lane * 4 + 3];
  float wl0 = -w0 * L2E, wl1 = -w1 * L2E, wl2 = -w2 * L2E, wl3 = -w3 * L2E;
  float bl0 = -b0 * L2E, bl1 = -b1 * L2E, bl2 = -b2 * L2E, bl3 = -b3 * L2E;
  float a0 = 0.f, a1 = 0.f, a2 = 0.f, a3 = 0.f;
  int p0 = ptr[n], p1 = ptr[n + 1];
  for (int p = p0; p < p1; p++) {
    float dn = dnc[p];
    float x0 = fmaf(dn, w0, b0), e0 = exp2f(fmaf(dn, wl0, bl0));
    float x1 = fmaf(dn, w1, b1), e1 = exp2f(fmaf(dn, wl1, bl1));
    float x2 = fmaf(dn, w2, b2), e2 = exp2f(fmaf(dn, wl2, bl2));
    float x3 = fmaf(dn, w3, b3), e3 = exp2f(fmaf(dn, wl3, bl3));
    a0 += x0 * __builtin_amdgcn_rcpf(1.f + e0);
    a1 += x1 * __builtin_amdgcn_rcpf(1.f + e1);
    a2 += x2 * __builtin_amdgcn_rcpf(1.f + e2);
    a3 += x3 * __builtin_amdgcn_rcpf(1.f + e3);
  }
  ushort4 ov;
  ov.x = f2bf(a0); ov.y = f2bf(a1); ov.z = f2bf(a2); ov.w = f2bf(a3);
  *reinterpret_cast<ushort4*>(&Sbf[(size_t)n * 256 + lane * 4]) = ov;
}

__global__ void cvt_bf(const float* __restrict__ src, u16* __restrict__ dst, int n) {
  int t = blockIdx.x * 256 + threadIdx.x;
  if (t < n) dst[t] = f2bf(src[t]);
}

extern "C" void kernel_launch(void* const* d_in, const int* in_sizes, int n_in,
                              void* d_out, int out_size, void* d_ws, size_t ws_size,
                              hipStream_t stream) {
  const float* h     = (const float*)d_in[0];
  const float* pos   = (const float*)d_in[1];
  const int*   eidx  = (const int*)d_in[2];
  const float* eattr = (const float*)d_in[3];
  const float* W_e1 = (const float*)d_in[4];  const float* b_e1 = (const float*)d_in[5];
  const float* g_e  = (const float*)d_in[6];  const float* be_ln = (const float*)d_in[7];
  const float* W_e2 = (const float*)d_in[8];  const float* b_e2 = (const float*)d_in[9];
  const float* W_n1 = (const float*)d_in[10]; const float* b_n1 = (const float*)d_in[11];
  const float* g_n  = (const float*)d_in[12]; const float* bn_ln = (const float*)d_in[13];
  const float* W_n2 = (const float*)d_in[14]; const float* b_n2 = (const float*)d_in[15];
  const float* g_o  = (const float*)d_in[16]; const float* bo_ln = (const float*)d_in[17];
  const float* W_c1 = (const float*)d_in[18]; const float* b_c1 = (const float*)d_in[19];
  const float* W_c2 = (const float*)d_in[20];
  const float* W_a  = (const float*)d_in[21]; const float* b_a = (const float*)d_in[22];
  const float* W_f1 = (const float*)d_in[23]; const float* b_f1 = (const float*)d_in[24];
  const float* W_f2 = (const float*)d_in[25]; const float* b_f2 = (const float*)d_in[26];

  float* outp = (float*)d_out;
  float* out_pos = outp + (size_t)NN * 256;

  char* base = (char*)d_ws;
  size_t off = 0;
  auto alloc = [&](size_t bytes) -> void* {
    off = (off + 255) & ~(size_t)255;
    void* p = base + off;
    off += bytes;
    return p;
  };
  const int NP = 50048;  // padded node count (multiple of 128)
  // ---- persistent (~167 MB) ----
  u16* We1Ta = (u16*)alloc((size_t)512 * 256 * 2);
  u16* We1Tb = (u16*)alloc((size_t)512 * 256 * 2);
  u16* We2f  = (u16*)alloc((size_t)256 * 512 * 2);
  u16* Wc1f  = (u16*)alloc((size_t)256 * 256 * 2);
  u16* Wn1T  = (u16*)alloc((size_t)512 * 512 * 2);
  u16* Wn2T  = (u16*)alloc((size_t)256 * 512 * 2);
  u16* Wf2T  = (u16*)alloc((size_t)256 * 256 * 2);
  float* Wt  = (float*)alloc((size_t)512 * 16 * 4);
  u16* hbf   = (u16*)alloc((size_t)NP * 256 * 2);
  float* dist = (float*)alloc((size_t)EE * 4);
  int*   icnt = (int*)alloc((size_t)NN * 4);
  int*   ptr  = (int*)alloc((size_t)(NN + 1) * 4);
  int*   head = (int*)alloc((size_t)NN * 4);
  int*   perm = (int*)alloc((size_t)EE * 4);
  int*   sperm = (int*)alloc((size_t)EE * 4);
  float* cntf = (float*)alloc((size_t)NN * 4);
  float* cagg = (float*)alloc((size_t)NN * 12);
  int*   meta = (int*)alloc((size_t)8192);
  u16*   aggbf = (u16*)alloc((size_t)NP * 256 * 2);
  u16*   P1 = (u16*)alloc((size_t)NP * 512 * 2);      // phase B: t2 overlay
  u16*   P2 = (u16*)alloc((size_t)NP * 512 * 2);      // phase B: hupd overlay

  // ---- edge arena (520 B/edge) + per-chunk col-sort scratch ----
  off = (off + 255) & ~(size_t)255;
  char* arena = base + off;
  size_t avail = (ws_size > off) ? ws_size - off : 0;
  const size_t SBF_BYTES = (size_t)NP * 256 * 2;
  const int ladder[6] = {16384, 12288, 8192, 4096, 2048, 1024};
  int CN = 1024;
  for (int li = 0; li < 6; li++) {
    int nchl = (NN + ladder[li] - 1) / ladder[li];
    size_t need = (size_t)((size_t)ladder[li] * 16 + 4096) * 520 +
                  (size_t)nchl * NN * 4 + 512;
    if (need < SBF_BYTES) need = SBF_BYTES;
    if (need <= avail) { CN = ladder[li]; break; }
  }
  const int capE = CN * 16 + 4096;
  const int nch = (NN + CN - 1) / CN;
  u16*   mBuf = (u16*)arena;                             // [capE][256]
  float* att  = (float*)(arena + (size_t)capE * 512);    // [capE]
  float* cw   = (float*)(arena + (size_t)capE * 516);    // [capE]
  int*   csort = (int*)(arena + (((size_t)capE * 520 + 255) & ~(size_t)255)); // [nch][NN]
  u16*   Sbf  = (u16*)arena;                             // [NP][256] (phase C)
  u16*   t2   = P1;                                      // [NP][512] (phase B)
  float* hupd = (float*)P2;                              // [NP][256] f32 (phase B)

  const int* rowp = eidx;
  const int* colp = eidx + EE;

  hipMemsetAsync(icnt, 0, (size_t)NN * 4, stream);
  hipMemsetAsync(csort, 0, (size_t)nch * NN * 4, stream);

  // ---- weight prep ----
  wtrans<<<(512 * 256 + 255) / 256, 256, 0, stream>>>(W_e1, We1Ta, 256, 512, 256);
  wtrans<<<(512 * 256 + 255) / 256, 256, 0, stream>>>(W_e1 + (size_t)256 * 512, We1Tb, 256, 512, 256);
  build_wf<<<(256 * 512 + 255) / 256, 256, 0, stream>>>(W_e2, We2f, 512, 256);
  build_wf<<<(256 * 256 + 255) / 256, 256, 0, stream>>>(W_c1, Wc1f, 256, 256);
  wtrans<<<(512 * 512 + 255) / 256, 256, 0, stream>>>(W_n1, Wn1T, 512, 512, 512);
  wtrans<<<(256 * 512 + 255) / 256, 256, 0, stream>>>(W_n2, Wn2T, 512, 256, 512);
  wtrans<<<(256 * 256 + 255) / 256, 256, 0, stream>>>(W_f2, Wf2T, 256, 256, 256);
  build_wt<<<(512 * 16 + 255) / 256, 256, 0, stream>>>(W_e1, b_e1, Wt);
  cvt_bf<<<(NN * 256 + 255) / 256, 256, 0, stream>>>(h, hbf, NN * 256);

  // ---- CSR build + per-chunk col sort ----
  edge_geom<<<(EE + 255) / 256, 256, 0, stream>>>(pos, rowp, colp, dist, icnt);
  scan_ptr<<<1, 1024, 0, stream>>>(icnt, ptr);
  copy_head<<<(NN + 255) / 256, 256, 0, stream>>>(ptr, head, cntf);
  fill_perm<<<(EE + 255) / 256, 256, 0, stream>>>(rowp, head, perm);
  chunk_meta<<<(nch + 255) / 256, 256, 0, stream>>>(ptr, meta, CN, nch, capE);
  chist<<<(EE + 255) / 256, 256, 0, stream>>>(colp, perm, meta, nch, csort);
  cscan<<<nch, 1024, 0, stream>>>(csort);
  cscatter<<<(EE + 255) / 256, 256, 0, stream>>>(colp, perm, meta, nch, csort, sperm);

  // ---- P1 = h@We1[0:256], P2 = h@We1[256:512] ----
  dim3 gp(NP / 128, 4);
  gemm128<7, 0><<<gp, 256, 0, stream>>>(hbf, We1Ta, nullptr, P1, NN, 512, 256,
                                        nullptr, nullptr, nullptr, nullptr, 0.f);
  gemm128<7, 0><<<gp, 256, 0, stream>>>(hbf, We1Tb, nullptr, P2, NN, 512, 256,
                                        nullptr, nullptr, nullptr, nullptr, 0.f);

  // ---- phase A: fused edge pipeline (BM=64, col-sorted order) ----
  for (int c = 0; c < nch; c++) {
    int nlo = c * CN;
    int cn = NN - nlo; if (cn > CN) cn = CN;
    edge_fused<<<capE / 64, 256, 0, stream>>>(
        P1, P2, dist, eattr, Wt, g_e, be_ln, b_e2, b_c1, W_a, b_a, W_c2,
        We2f, Wc1f, rowp, colp, perm, sperm, meta, c, mBuf, att, cw);
    node_agg<<<(cn + 3) / 4, 256, 0, stream>>>(mBuf, att, cw, pos, colp, perm, ptr,
                                               meta, c, aggbf, cagg, nlo, cn);
  }

  // ---- phase B: node pipeline ----
  gemm128<0, 2><<<gp, 256, 0, stream>>>(nullptr, Wn1T, b_n1, t2, NN, 512, 512,
                                        hbf, aggbf, nullptr, nullptr, 0.f);
  ln_512<<<NN, 128, 0, stream>>>(t2, g_n, bn_ln, NN);
  dim3 g5(NP / 128, 2);
  gemm128<1, 0><<<g5, 256, 0, stream>>>(t2, Wn2T, b_n2, hupd, NN, 256, 512,
                                        nullptr, nullptr, nullptr, nullptr, 0.f);
  hmid_ln<<<NN, 64, 0, stream>>>(h, hupd, g_o, bo_ln, outp);

  // ---- phase C: coords + feedback ----
  posnew_k<<<(NN * 3 + 255) / 256, 256, 0, stream>>>(pos, cagg, out_pos);
  dnn_k<<<(EE + 255) / 256, 256, 0, stream>>>(out_pos, rowp, colp, perm, dist);
  edge_fb2<<<(NN + 3) / 4, 256, 0, stream>>>(dist, ptr, W_f1, b_f1, Sbf);
  gemm128<2, 0><<<g5, 256, 0, stream>>>(Sbf, Wf2T, nullptr, outp, NN, 256, 256,
                                        nullptr, nullptr, cntf, b_f2, 0.1f);
}

// Round 18
// 1937.111 us; speedup vs baseline: 1.1400x; 1.1400x over previous
//
#include <hip/hip_runtime.h>

// EGNN layer: N=50000 nodes, E=800000 edges, H=256.
// Round 18: revert to R14 exactly - the measured optimum (1945us).
// Evidence accumulated R13-R17: edge-phase HBM gather traffic is ~0.84KB/edge
// invariant to chunk size/count (R13,R14), access order (R17 col-sort:
// FETCH got WORSE at equal CN), and cache hints (R16 NT: neutral). In-kernel
// e1-GEMM (R15) spills registers. Structure: BM=64 fused edge kernel
// (eadd + barrier-free MFMA m-GEMM + c1-GEMM, fragment-ordered B operands),
// CN ladder (12288 fits -> 5 chunks), P1/P2 node-level decomposition of the
// edge GEMM1, CSR counting sort -> zero f32 atomics end-to-end.

#define NN 50000
#define EE 800000

typedef unsigned short u16;
typedef float f32x4 __attribute__((ext_vector_type(4)));
typedef short bf16x8 __attribute__((ext_vector_type(8)));
typedef unsigned uint4v __attribute__((ext_vector_type(4)));

__device__ __forceinline__ u16 f2bf(float f) {
  unsigned u = __float_as_uint(f);
  u = (u + 0x7FFFu + ((u >> 16) & 1u)) >> 16;
  return (u16)u;
}
__device__ __forceinline__ float bf2f(u16 s) {
  return __uint_as_float(((unsigned)s) << 16);
}
__device__ __forceinline__ float bflo(unsigned u) { return __uint_as_float(u << 16); }
__device__ __forceinline__ float bfhi(unsigned u) { return __uint_as_float(u & 0xFFFF0000u); }
__device__ __forceinline__ float silu_f(float x) {
  return x * __builtin_amdgcn_rcpf(1.f + exp2f(x * -1.44269504f));
}

__device__ __forceinline__ void gload16(const void* g, void* l) {
  __builtin_amdgcn_global_load_lds(
      (const __attribute__((address_space(1))) void*)g,
      (__attribute__((address_space(3))) void*)l, 16, 0, 0);
}

// ---------------- fused edge kernel (BM=64, barrier-free GEMMs) --------------
__global__ __launch_bounds__(256, 2) void edge_fused(
    const u16* __restrict__ P1, const u16* __restrict__ P2,
    const float* __restrict__ dist, const float* __restrict__ eattr,
    const float* __restrict__ Wt, const float* __restrict__ ge,
    const float* __restrict__ beln, const float* __restrict__ be2,
    const float* __restrict__ bc1, const float* __restrict__ Wa,
    const float* __restrict__ ba, const float* __restrict__ Wc2,
    const u16* __restrict__ We2f, const u16* __restrict__ Wc1f,
    const int* __restrict__ rowp, const int* __restrict__ colp,
    const int* __restrict__ perm, const int* __restrict__ meta, int cidx,
    u16* __restrict__ mBuf, float* __restrict__ att, float* __restrict__ cwv) {
  const int M = meta[2 * cidx + 1];
  const int eb = meta[2 * cidx];
  const int m0 = blockIdx.x * 64;
  if (m0 >= M) return;
  __shared__ __align__(16) u16 At[64][512];     // 64 KB; P3: Mt rows 0..31, red row 32
  const int tid = threadIdx.x, w = tid >> 6, lane = tid & 63;
  const int l15 = lane & 15, kq = lane >> 4;
  const int ch0 = lane * 8;

  // ---- phase 1: eadd (metadata pre-staged lane-parallel) ----
  {
    int le0 = m0 + w * 16 + (lane & 15);
    if (le0 > M - 1) le0 = M - 1;
    const int e_l = perm[eb + le0];
    const int r_l = rowp[e_l];
    const int c_l = colp[e_l];
    const float dd_l = dist[e_l];

    float wreg[8][15], gg[8], bb[8];
#pragma unroll
    for (int i = 0; i < 8; i++) {
#pragma unroll
      for (int j = 0; j < 15; j++) wreg[i][j] = Wt[(ch0 + i) * 16 + j];
      gg[i] = ge[ch0 + i]; bb[i] = beln[ch0 + i];
    }
#pragma unroll 2
    for (int rr = 0; rr < 16; rr++) {
      int e = __shfl(e_l, rr);
      int r = __shfl(r_l, rr);
      int c = __shfl(c_l, rr);
      float dd = __shfl(dd_l, rr);
      float fa[13];
#pragma unroll
      for (int j = 0; j < 13; j++) fa[j] = eattr[(size_t)e * 13 + j];
      uint4v u1 = *(const uint4v*)&P1[(size_t)r * 512 + ch0];
      uint4v u2 = *(const uint4v*)&P2[(size_t)c * 512 + ch0];
      float sv[8], s1 = 0.f, s2 = 0.f;
#pragma unroll
      for (int i = 0; i < 8; i++) {
        float xp = (i & 1) ? bfhi(u1[i >> 1]) : bflo(u1[i >> 1]);
        float xq = (i & 1) ? bfhi(u2[i >> 1]) : bflo(u2[i >> 1]);
        float x = xp + xq + wreg[i][0] + dd * wreg[i][1];
#pragma unroll
        for (int j = 0; j < 13; j++) x = fmaf(fa[j], wreg[i][2 + j], x);
        float s = silu_f(x);
        sv[i] = s; s1 += s; s2 += s * s;
      }
#pragma unroll
      for (int o = 32; o; o >>= 1) { s1 += __shfl_xor(s1, o); s2 += __shfl_xor(s2, o); }
      float mu = s1 * (1.f / 512.f);
      float inv = rsqrtf(s2 * (1.f / 512.f) - mu * mu + 1e-5f);
      int row = w * 16 + rr;
      u16 ot[8];
#pragma unroll
      for (int i = 0; i < 8; i++) ot[i] = f2bf((sv[i] - mu) * inv * gg[i] + bb[i]);
      *(uint4v*)&At[row][(lane ^ (row & 7)) * 8] = *(const uint4v*)ot;
    }
  }
  __syncthreads();

  // ---- phase 2: m-GEMM K=512, barrier-free ----
  f32x4 acc[4][4] = {};
  {
    const u16* Bw = We2f + (size_t)w * 32768;   // 16 ks x 4 j x 64 lanes x 8
    __builtin_amdgcn_s_setprio(1);
#pragma unroll 4
    for (int ks = 0; ks < 16; ks++) {
      bf16x8 bfr[4], af[4];
#pragma unroll
      for (int j = 0; j < 4; j++)
        bfr[j] = *(const bf16x8*)&Bw[((ks * 4 + j) * 64 + lane) * 8];
#pragma unroll
      for (int i = 0; i < 4; i++) {
        int rw = i * 16 + l15;
        af[i] = *(const bf16x8*)&At[rw][((ks * 4 + kq) ^ (rw & 7)) * 8];
      }
#pragma unroll
      for (int i = 0; i < 4; i++)
#pragma unroll
        for (int j = 0; j < 4; j++)
          acc[i][j] = __builtin_amdgcn_mfma_f32_16x16x32_bf16(af[i], bfr[j], acc[i][j], 0, 0, 0);
    }
    __builtin_amdgcn_s_setprio(0);
  }
  __syncthreads();   // all At reads done before Mt overwrite

  // ---- m epilogue: mBuf + Mt(LDS) + att partials ----
  u16* Mt = &At[0][0];                  // [64][256] swizzled = At rows 0..31
  float* red = (float*)&At[32][0];      // [64][4]
  float ds_a[4][4];
#pragma unroll
  for (int i = 0; i < 4; i++)
#pragma unroll
    for (int t = 0; t < 4; t++) ds_a[i][t] = 0.f;
#pragma unroll
  for (int j = 0; j < 4; j++) {
    int col = w * 64 + j * 16 + l15;
    float bz = be2[col], wa = Wa[col];
    int slot = col >> 3, offc = col & 7;
#pragma unroll
    for (int i = 0; i < 4; i++) {
#pragma unroll
      for (int t = 0; t < 4; t++) {
        int row = i * 16 + kq * 4 + t;
        float sv = silu_f(acc[i][j][t] + bz);
        int le = m0 + row;
        if (le < M) mBuf[(size_t)le * 256 + col] = f2bf(sv);
        Mt[row * 256 + ((slot ^ (row & 7)) << 3) + offc] = f2bf(sv);
        ds_a[i][t] += sv * wa;
      }
    }
  }
#pragma unroll
  for (int i = 0; i < 4; i++)
#pragma unroll
    for (int t = 0; t < 4; t++) {
      float s = ds_a[i][t];
      s += __shfl_xor(s, 1); s += __shfl_xor(s, 2);
      s += __shfl_xor(s, 4); s += __shfl_xor(s, 8);
      if (l15 == 0) red[(i * 16 + kq * 4 + t) * 4 + w] = s;
    }
  __syncthreads();
  if (tid < 64) {
    int le = m0 + tid;
    if (le < M) {
      float s = red[tid * 4] + red[tid * 4 + 1] + red[tid * 4 + 2] + red[tid * 4 + 3] + ba[0];
      att[le] = __builtin_amdgcn_rcpf(1.f + exp2f(s * -1.44269504f));
    }
  }

  // ---- phase 3: c1-GEMM K=256 over Mt, barrier-free ----
  f32x4 ac2[4][4] = {};
  {
    const u16* Bw = Wc1f + (size_t)w * 16384;   // 8 ks x 4 j x 64 lanes x 8
    __builtin_amdgcn_s_setprio(1);
#pragma unroll 4
    for (int ks = 0; ks < 8; ks++) {
      bf16x8 bfr[4], af[4];
#pragma unroll
      for (int j = 0; j < 4; j++)
        bfr[j] = *(const bf16x8*)&Bw[((ks * 4 + j) * 64 + lane) * 8];
#pragma unroll
      for (int i = 0; i < 4; i++) {
        int rw = i * 16 + l15;
        af[i] = *(const bf16x8*)&Mt[rw * 256 + (((ks * 4 + kq) ^ (rw & 7)) << 3)];
      }
#pragma unroll
      for (int i = 0; i < 4; i++)
#pragma unroll
        for (int j = 0; j < 4; j++)
          ac2[i][j] = __builtin_amdgcn_mfma_f32_16x16x32_bf16(af[i], bfr[j], ac2[i][j], 0, 0, 0);
    }
    __builtin_amdgcn_s_setprio(0);
  }
  float ds_c[4][4];
#pragma unroll
  for (int i = 0; i < 4; i++)
#pragma unroll
    for (int t = 0; t < 4; t++) ds_c[i][t] = 0.f;
#pragma unroll
  for (int j = 0; j < 4; j++) {
    int col = w * 64 + j * 16 + l15;
    float bz = bc1[col], wc = Wc2[col];
#pragma unroll
    for (int i = 0; i < 4; i++)
#pragma unroll
      for (int t = 0; t < 4; t++)
        ds_c[i][t] += silu_f(ac2[i][j][t] + bz) * wc;
  }
  __syncthreads();   // red reads (att) done before overwrite
#pragma unroll
  for (int i = 0; i < 4; i++)
#pragma unroll
    for (int t = 0; t < 4; t++) {
      float s = ds_c[i][t];
      s += __shfl_xor(s, 1); s += __shfl_xor(s, 2);
      s += __shfl_xor(s, 4); s += __shfl_xor(s, 8);
      if (l15 == 0) red[(i * 16 + kq * 4 + t) * 4 + w] = s;
    }
  __syncthreads();
  if (tid < 64) {
    int le = m0 + tid;
    if (le < M)
      cwv[le] = red[tid * 4] + red[tid * 4 + 1] + red[tid * 4 + 2] + red[tid * 4 + 3];
  }
}

// ---------------- 128x128 MFMA GEMM (node/feedback paths) --------------------
// MODE 0: silu->bf16 ; 1: ->f32 ; 2: f32 += scale*(acc+cnt*b2) ; 7: ->bf16 no bias
// GATHER 0: A normal ; 2: node rows [hbf|src2]
template <int MODE, int GATHER>
__global__ __launch_bounds__(256) void gemm128(
    const u16* __restrict__ A, const u16* __restrict__ BT,
    const float* __restrict__ bias, void* __restrict__ outp,
    int Mh, int Nc, int K,
    const u16* __restrict__ hbf, const u16* __restrict__ src2,
    const float* __restrict__ cnt, const float* __restrict__ b2, float scale) {
  const int M = Mh;
  const int m0 = blockIdx.x * 128, n0 = blockIdx.y * 128;
  if (m0 >= M) return;
  __shared__ __align__(16) u16 As[128][32];
  __shared__ __align__(16) u16 Bs[128][32];
  const int tid = threadIdx.x, w = tid >> 6, lane = tid & 63;
  const int srow = lane >> 2, sch = (lane & 3) * 8;
  const int r0 = w * 32 + srow, r1 = r0 + 16;

  u16* as0 = &As[w * 32][0];
  u16* as1 = &As[w * 32 + 16][0];
  u16* bs0 = &Bs[w * 32][0];
  u16* bs1 = &Bs[w * 32 + 16][0];

  const u16 *a0r, *a0c, *a1r, *a1c;
  a0c = a1c = nullptr;
  if (GATHER == 2) {
    int q0 = m0 + r0; if (q0 > M - 1) q0 = M - 1;
    int q1 = m0 + r1; if (q1 > M - 1) q1 = M - 1;
    a0r = hbf + (size_t)q0 * 256;  a0c = src2 + (size_t)q0 * 256;
    a1r = hbf + (size_t)q1 * 256;  a1c = src2 + (size_t)q1 * 256;
  } else {
    a0r = A + (size_t)(m0 + r0) * K;
    a1r = A + (size_t)(m0 + r1) * K;
  }
  const u16* b0 = BT + (size_t)(n0 + r0) * K;
  const u16* b1 = BT + (size_t)(n0 + r1) * K;

  f32x4 acc[4][4] = {};
  const int l15 = lane & 15, ko = (lane >> 4) * 8;
  const int ar0 = (w >> 1) * 64, br0 = (w & 1) * 64;

  for (int k0 = 0; k0 < K; k0 += 32) {
    const u16 *pa0, *pa1;
    if (GATHER == 2) {
      if (k0 < 256) { pa0 = a0r + k0;         pa1 = a1r + k0; }
      else          { pa0 = a0c + (k0 - 256); pa1 = a1c + (k0 - 256); }
    } else { pa0 = a0r + k0; pa1 = a1r + k0; }
    gload16(pa0 + sch, as0);
    gload16(pa1 + sch, as1);
    gload16(b0 + k0 + sch, bs0);
    gload16(b1 + k0 + sch, bs1);
    __syncthreads();
    bf16x8 af[4], bfr[4];
#pragma unroll
    for (int i = 0; i < 4; i++)
      af[i] = *reinterpret_cast<const bf16x8*>(&As[ar0 + i * 16 + l15][ko]);
#pragma unroll
    for (int j = 0; j < 4; j++)
      bfr[j] = *reinterpret_cast<const bf16x8*>(&Bs[br0 + j * 16 + l15][ko]);
#pragma unroll
    for (int i = 0; i < 4; i++)
#pragma unroll
      for (int j = 0; j < 4; j++)
        acc[i][j] = __builtin_amdgcn_mfma_f32_16x16x32_bf16(af[i], bfr[j], acc[i][j], 0, 0, 0);
    __syncthreads();
  }

  const int rb = m0 + ar0 + ((lane >> 4) << 2);
#pragma unroll
  for (int j = 0; j < 4; j++) {
    const int gc = n0 + br0 + j * 16 + l15;
    const float bz = (MODE == 2 || MODE == 7) ? 0.f : bias[gc];
#pragma unroll
    for (int i = 0; i < 4; i++) {
#pragma unroll
      for (int t = 0; t < 4; t++) {
        const int gr = rb + i * 16 + t;
        if (gr >= M) continue;
        float v = acc[i][j][t] + bz;
        size_t oi = (size_t)gr * Nc + gc;
        if (MODE == 0)      ((u16*)outp)[oi] = f2bf(silu_f(v));
        else if (MODE == 1) ((float*)outp)[oi] = v;
        else if (MODE == 2) ((float*)outp)[oi] += scale * (v + cnt[gr] * b2[gc]);
        else if (MODE == 7) ((u16*)outp)[oi] = f2bf(v);
      }
    }
  }
}

// ---------------- weight transpose + bf16: src[K,N] -> dst[N,Kpad] -----------
__global__ void wtrans(const float* __restrict__ src, u16* __restrict__ dst,
                       int K, int Nn, int Kpad) {
  int t = blockIdx.x * 256 + threadIdx.x;
  if (t >= Nn * Kpad) return;
  int n = t / Kpad, k = t - n * Kpad;
  float v = (k < K) ? src[(size_t)k * Nn + n] : 0.f;
  dst[t] = f2bf(v);
}

// fragment-ordered B for barrier-free fused GEMMs
__global__ void build_wf(const float* __restrict__ src, u16* __restrict__ dst,
                         int K, int Nn) {
  int t = blockIdx.x * 256 + threadIdx.x;
  if (t >= Nn * K) return;
  int i = t & 7;
  int lane = (t >> 3) & 63;
  int rest = t >> 9;
  int j = rest & 3;
  int rest2 = rest >> 2;
  int KS = K >> 5;
  int wv = rest2 / KS, ks = rest2 - wv * KS;
  int n = wv * 64 + j * 16 + (lane & 15);
  int k = ks * 32 + (lane >> 4) * 8 + i;
  dst[t] = f2bf(src[(size_t)k * Nn + n]);
}

// Wt[n][16] = {b_e1[n], W_e1[512][n], W_e1[513..525][n], 0}
__global__ void build_wt(const float* __restrict__ W_e1, const float* __restrict__ b_e1,
                         float* __restrict__ Wt) {
  int t = blockIdx.x * 256 + threadIdx.x;
  if (t >= 512 * 16) return;
  int n = t >> 4, j = t & 15;
  float v = 0.f;
  if (j == 0) v = b_e1[n];
  else if (j < 15) v = W_e1[(size_t)(511 + j) * 512 + n];
  Wt[t] = v;
}

__global__ void edge_geom(const float* __restrict__ pos, const int* __restrict__ row,
                          const int* __restrict__ colx, float* __restrict__ dist,
                          int* __restrict__ icnt) {
  int e = blockIdx.x * 256 + threadIdx.x;
  if (e >= EE) return;
  int r = row[e], c = colx[e];
  float d0 = pos[r * 3 + 0] - pos[c * 3 + 0];
  float d1 = pos[r * 3 + 1] - pos[c * 3 + 1];
  float d2 = pos[r * 3 + 2] - pos[c * 3 + 2];
  dist[e] = fmaxf(sqrtf(d0 * d0 + d1 * d1 + d2 * d2), 1e-5f);
  atomicAdd(&icnt[r], 1);
}

__global__ __launch_bounds__(1024) void scan_ptr(const int* __restrict__ icnt,
                                                 int* __restrict__ ptr) {
  __shared__ int ls[1024];
  const int t = threadIdx.x;
  const int SEG = (NN + 1023) / 1024;
  int s0 = t * SEG;
  int s1 = s0 + SEG; if (s1 > NN) s1 = NN;
  int sum = 0;
  for (int i = s0; i < s1; i++) sum += icnt[i];
  ls[t] = sum;
  __syncthreads();
  for (int off = 1; off < 1024; off <<= 1) {
    int v = (t >= off) ? ls[t - off] : 0;
    __syncthreads();
    ls[t] += v;
    __syncthreads();
  }
  int run = ls[t] - sum;
  for (int i = s0; i < s1; i++) { ptr[i] = run; run += icnt[i]; }
  if (t == 1023) ptr[NN] = ls[1023];
}

__global__ void copy_head(const int* __restrict__ ptr, int* __restrict__ head,
                          float* __restrict__ cntf) {
  int n = blockIdx.x * 256 + threadIdx.x;
  if (n >= NN) return;
  head[n] = ptr[n];
  cntf[n] = (float)(ptr[n + 1] - ptr[n]);
}

__global__ void fill_perm(const int* __restrict__ row, int* __restrict__ head,
                          int* __restrict__ perm) {
  int e = blockIdx.x * 256 + threadIdx.x;
  if (e >= EE) return;
  int p = atomicAdd(&head[row[e]], 1);
  perm[p] = e;
}

__global__ void chunk_meta(const int* __restrict__ ptr, int* __restrict__ meta,
                           int CN, int nch, int capE) {
  int c = blockIdx.x * 256 + threadIdx.x;
  if (c >= nch) return;
  int lo = c * CN;
  int hi = lo + CN; if (hi > NN) hi = NN;
  int b = ptr[lo];
  int cc = ptr[hi] - b;
  if (cc > capE) cc = capE;
  meta[2 * c + 0] = b;
  meta[2 * c + 1] = cc;
}

// ---------------- in-place row LayerNorm on bf16, D=512 (node phase) ---------
__global__ __launch_bounds__(128) void ln_512(u16* __restrict__ t,
                                              const float* __restrict__ g,
                                              const float* __restrict__ b, int Mh) {
  int row = blockIdx.x;
  if (row >= Mh) return;
  int tid = threadIdx.x;
  size_t base = (size_t)row * 512 + tid * 4;
  ushort4 xv = *reinterpret_cast<const ushort4*>(&t[base]);
  float x0 = bf2f(xv.x), x1 = bf2f(xv.y), x2 = bf2f(xv.z), x3 = bf2f(xv.w);
  float s1 = x0 + x1 + x2 + x3;
  float s2 = x0 * x0 + x1 * x1 + x2 * x2 + x3 * x3;
  for (int o = 32; o; o >>= 1) { s1 += __shfl_xor(s1, o); s2 += __shfl_xor(s2, o); }
  __shared__ float red[4];
  if ((tid & 63) == 0) { red[tid >> 6] = s1; red[2 + (tid >> 6)] = s2; }
  __syncthreads();
  s1 = red[0] + red[1]; s2 = red[2] + red[3];
  float mu = s1 * (1.f / 512.f);
  float var = s2 * (1.f / 512.f) - mu * mu;
  float inv = rsqrtf(var + 1e-5f);
  int c = tid * 4;
  ushort4 yv;
  yv.x = f2bf((x0 - mu) * inv * g[c + 0] + b[c + 0]);
  yv.y = f2bf((x1 - mu) * inv * g[c + 1] + b[c + 1]);
  yv.z = f2bf((x2 - mu) * inv * g[c + 2] + b[c + 2]);
  yv.w = f2bf((x3 - mu) * inv * g[c + 3] + b[c + 3]);
  *reinterpret_cast<ushort4*>(&t[base]) = yv;
}

// ---------------- per-node aggregation (scalar att/cw) -----------------------
__global__ __launch_bounds__(256) void node_agg(
    const u16* __restrict__ m, const float* __restrict__ att,
    const float* __restrict__ cwv,
    const float* __restrict__ pos, const int* __restrict__ colx,
    const int* __restrict__ perm, const int* __restrict__ ptr,
    const int* __restrict__ meta, int cidx,
    u16* __restrict__ aggbf, float* __restrict__ cagg, int nlo, int cn) {
  int w = threadIdx.x >> 6, lane = threadIdx.x & 63;
  int nl = blockIdx.x * 4 + w;
  if (nl >= cn) return;
  int n = nlo + nl;
  int base = meta[2 * cidx];
  int p0 = ptr[n], p1 = ptr[n + 1];
  const int half = lane >> 5, ch = (lane & 31) * 8;
  float a[8] = {};
  for (int p = p0 + half; p < p1; p += 2) {
    int le = p - base;
    float at = att[le];
    uint4v mv = *reinterpret_cast<const uint4v*>(&m[(size_t)le * 256 + ch]);
#pragma unroll
    for (int i = 0; i < 4; i++) {
      a[2 * i]     += at * bflo(mv[i]);
      a[2 * i + 1] += at * bfhi(mv[i]);
    }
  }
#pragma unroll
  for (int i = 0; i < 8; i++) a[i] += __shfl_xor(a[i], 32);
  if (half == 0) {
    u16 ot[8];
#pragma unroll
    for (int i = 0; i < 8; i++) ot[i] = f2bf(a[i]);
    *reinterpret_cast<uint4v*>(&aggbf[(size_t)n * 256 + ch]) =
        *reinterpret_cast<const uint4v*>(ot);
  }
  float prx = pos[n * 3 + 0], pry = pos[n * 3 + 1], prz = pos[n * 3 + 2];
  float sx = 0.f, sy = 0.f, sz = 0.f;
  for (int p = p0 + lane; p < p1; p += 64) {
    int le = p - base;
    float cv = cwv[le];
    int c = colx[perm[p]];
    sx += cv * (prx - pos[c * 3 + 0]);
    sy += cv * (pry - pos[c * 3 + 1]);
    sz += cv * (prz - pos[c * 3 + 2]);
  }
#pragma unroll
  for (int o = 32; o; o >>= 1) {
    sx += __shfl_xor(sx, o); sy += __shfl_xor(sy, o); sz += __shfl_xor(sz, o);
  }
  if (lane == 0) {
    cagg[n * 3 + 0] = sx; cagg[n * 3 + 1] = sy; cagg[n * 3 + 2] = sz;
  }
}

__global__ __launch_bounds__(64) void hmid_ln(const float* __restrict__ h,
                                              const float* __restrict__ hupd,
                                              const float* __restrict__ g,
                                              const float* __restrict__ b,
                                              float* __restrict__ outp) {
  int row = blockIdx.x, lane = threadIdx.x;
  size_t base = (size_t)row * 256 + lane * 4;
  float x[4];
#pragma unroll
  for (int i = 0; i < 4; i++) x[i] = h[base + i] + hupd[base + i];
  float s1 = x[0] + x[1] + x[2] + x[3];
  float s2 = x[0] * x[0] + x[1] * x[1] + x[2] * x[2] + x[3] * x[3];
  for (int o = 32; o; o >>= 1) { s1 += __shfl_xor(s1, o); s2 += __shfl_xor(s2, o); }
  float mu = s1 * (1.f / 256.f);
  float var = s2 * (1.f / 256.f) - mu * mu;
  float inv = rsqrtf(var + 1e-5f);
#pragma unroll
  for (int i = 0; i < 4; i++)
    outp[base + i] = (x[i] - mu) * inv * g[lane * 4 + i] + b[lane * 4 + i];
}

__global__ void posnew_k(const float* __restrict__ pos, const float* __restrict__ cagg,
                         float* __restrict__ op) {
  int t = blockIdx.x * 256 + threadIdx.x;
  if (t >= NN * 3) return;
  op[t] = pos[t] + cagg[t];
}

__global__ void dnn_k(const float* __restrict__ posn, const int* __restrict__ rowp,
                      const int* __restrict__ colp, const int* __restrict__ perm,
                      float* __restrict__ dnc) {
  int p = blockIdx.x * 256 + threadIdx.x;
  if (p >= EE) return;
  int e = perm[p];
  int r = rowp[e], c = colp[e];
  float d0 = posn[r * 3 + 0] - posn[c * 3 + 0];
  float d1 = posn[r * 3 + 1] - posn[c * 3 + 1];
  float d2 = posn[r * 3 + 2] - posn[c * 3 + 2];
  dnc[p] = fmaxf(sqrtf(d0 * d0 + d1 * d1 + d2 * d2), 1e-5f);
}

__global__ __launch_bounds__(256) void edge_fb2(
    const float* __restrict__ dnc, const int* __restrict__ ptr,
    const float* __restrict__ Wf1, const float* __restrict__ bf1,
    u16* __restrict__ Sbf) {
  int w = threadIdx.x >> 6, lane = threadIdx.x & 63;
  int n = blockIdx.x * 4 + w;
  if (n >= NN) return;
  const float L2E = 1.44269504f;
  float w0 = Wf1[lane * 4 + 0], w1 = Wf1[lane * 4 + 1];
  float w2 = Wf1[lane * 4 + 2], w3 = Wf1[lane * 4 + 3];
  float b0 = bf1[lane * 4 + 0], b1 = bf1[lane * 4 + 1];
  float b2 = bf1[lane * 4 + 2], b3 = bf1[lane * 4 + 3];
  float wl0 = -w0 * L2E, wl1 = -w1 * L2E, wl2 = -w2 * L2E, wl3 = -w3 * L2E;
  float bl0 = -b0 * L2E, bl1 = -b1 * L2E, bl2 = -b2 * L2E, bl3 = -b3 * L2E;
  float a0 = 0.f, a1 = 0.f, a2 = 0.f, a3 = 0.f;
  int p0 = ptr[n], p1 = ptr[n + 1];
  for (int p = p0; p < p1; p++) {
    float dn = dnc[p];
    float x0 = fmaf(dn, w0, b0), e0 = exp2f(fmaf(dn, wl0, bl0));
    float x1 = fmaf(dn, w1, b1), e1 = exp2f(fmaf(dn, wl1, bl1));
    float x2 = fmaf(dn, w2, b2), e2 = exp2f(fmaf(dn, wl2, bl2));
    float x3 = fmaf(dn, w3, b3), e3 = exp2f(fmaf(dn, wl3, bl3));
    a0 += x0 * __builtin_amdgcn_rcpf(1.f + e0);
    a1 += x1 * __builtin_amdgcn_rcpf(1.f + e1);
    a2 += x2 * __builtin_amdgcn_rcpf(1.f + e2);
    a3 += x3 * __builtin_amdgcn_rcpf(1.f + e3);
  }
  ushort4 ov;
  ov.x = f2bf(a0); ov.y = f2bf(a1); ov.z = f2bf(a2); ov.w = f2bf(a3);
  *reinterpret_cast<ushort4*>(&Sbf[(size_t)n * 256 + lane * 4]) = ov;
}

__global__ void cvt_bf(const float* __restrict__ src, u16* __restrict__ dst, int n) {
  int t = blockIdx.x * 256 + threadIdx.x;
  if (t < n) dst[t] = f2bf(src[t]);
}

extern "C" void kernel_launch(void* const* d_in, const int* in_sizes, int n_in,
                              void* d_out, int out_size, void* d_ws, size_t ws_size,
                              hipStream_t stream) {
  const float* h     = (const float*)d_in[0];
  const float* pos   = (const float*)d_in[1];
  const int*   eidx  = (const int*)d_in[2];
  const float* eattr = (const float*)d_in[3];
  const float* W_e1 = (const float*)d_in[4];  const float* b_e1 = (const float*)d_in[5];
  const float* g_e  = (const float*)d_in[6];  const float* be_ln = (const float*)d_in[7];
  const float* W_e2 = (const float*)d_in[8];  const float* b_e2 = (const float*)d_in[9];
  const float* W_n1 = (const float*)d_in[10]; const float* b_n1 = (const float*)d_in[11];
  const float* g_n  = (const float*)d_in[12]; const float* bn_ln = (const float*)d_in[13];
  const float* W_n2 = (const float*)d_in[14]; const float* b_n2 = (const float*)d_in[15];
  const float* g_o  = (const float*)d_in[16]; const float* bo_ln = (const float*)d_in[17];
  const float* W_c1 = (const float*)d_in[18]; const float* b_c1 = (const float*)d_in[19];
  const float* W_c2 = (const float*)d_in[20];
  const float* W_a  = (const float*)d_in[21]; const float* b_a = (const float*)d_in[22];
  const float* W_f1 = (const float*)d_in[23]; const float* b_f1 = (const float*)d_in[24];
  const float* W_f2 = (const float*)d_in[25]; const float* b_f2 = (const float*)d_in[26];

  float* outp = (float*)d_out;
  float* out_pos = outp + (size_t)NN * 256;

  char* base = (char*)d_ws;
  size_t off = 0;
  auto alloc = [&](size_t bytes) -> void* {
    off = (off + 255) & ~(size_t)255;
    void* p = base + off;
    off += bytes;
    return p;
  };
  const int NP = 50048;  // padded node count (multiple of 128)
  // ---- persistent (~164 MB) ----
  u16* We1Ta = (u16*)alloc((size_t)512 * 256 * 2);
  u16* We1Tb = (u16*)alloc((size_t)512 * 256 * 2);
  u16* We2f  = (u16*)alloc((size_t)256 * 512 * 2);   // fragment-ordered
  u16* Wc1f  = (u16*)alloc((size_t)256 * 256 * 2);   // fragment-ordered
  u16* Wn1T  = (u16*)alloc((size_t)512 * 512 * 2);
  u16* Wn2T  = (u16*)alloc((size_t)256 * 512 * 2);
  u16* Wf2T  = (u16*)alloc((size_t)256 * 256 * 2);
  float* Wt  = (float*)alloc((size_t)512 * 16 * 4);
  u16* hbf   = (u16*)alloc((size_t)NP * 256 * 2);
  float* dist = (float*)alloc((size_t)EE * 4);        // reused as dnc in phase C
  int*   icnt = (int*)alloc((size_t)NN * 4);
  int*   ptr  = (int*)alloc((size_t)(NN + 1) * 4);
  int*   head = (int*)alloc((size_t)NN * 4);
  int*   perm = (int*)alloc((size_t)EE * 4);
  float* cntf = (float*)alloc((size_t)NN * 4);
  float* cagg = (float*)alloc((size_t)NN * 12);
  int*   meta = (int*)alloc((size_t)8192);
  u16*   aggbf = (u16*)alloc((size_t)NP * 256 * 2);
  u16*   P1 = (u16*)alloc((size_t)NP * 512 * 2);      // phase B: t2 overlay
  u16*   P2 = (u16*)alloc((size_t)NP * 512 * 2);      // phase B: hupd overlay

  // ---- edge arena (520 B/edge); phase C: Sbf overlay ----
  off = (off + 255) & ~(size_t)255;
  char* arena = base + off;
  size_t avail = (ws_size > off) ? ws_size - off : 0;
  const size_t SBF_BYTES = (size_t)NP * 256 * 2;
  const int ladder[6] = {16384, 12288, 8192, 4096, 2048, 1024};
  int CN = 1024;
  for (int li = 0; li < 6; li++) {
    size_t need = (size_t)((size_t)ladder[li] * 16 + 4096) * 520;
    if (need < SBF_BYTES) need = SBF_BYTES;
    if (need <= avail) { CN = ladder[li]; break; }
  }
  const int capE = CN * 16 + 4096;                       // multiple of 64
  u16*   mBuf = (u16*)arena;                             // [capE][256]
  float* att  = (float*)(arena + (size_t)capE * 512);    // [capE]
  float* cw   = (float*)(arena + (size_t)capE * 516);    // [capE]
  u16*   Sbf  = (u16*)arena;                             // [NP][256] (phase C)
  u16*   t2   = P1;                                      // [NP][512] (phase B)
  float* hupd = (float*)P2;                              // [NP][256] f32 (phase B)

  const int* rowp = eidx;
  const int* colp = eidx + EE;
  const int nch = (NN + CN - 1) / CN;

  hipMemsetAsync(icnt, 0, (size_t)NN * 4, stream);

  // ---- weight prep ----
  wtrans<<<(512 * 256 + 255) / 256, 256, 0, stream>>>(W_e1, We1Ta, 256, 512, 256);
  wtrans<<<(512 * 256 + 255) / 256, 256, 0, stream>>>(W_e1 + (size_t)256 * 512, We1Tb, 256, 512, 256);
  build_wf<<<(256 * 512 + 255) / 256, 256, 0, stream>>>(W_e2, We2f, 512, 256);
  build_wf<<<(256 * 256 + 255) / 256, 256, 0, stream>>>(W_c1, Wc1f, 256, 256);
  wtrans<<<(512 * 512 + 255) / 256, 256, 0, stream>>>(W_n1, Wn1T, 512, 512, 512);
  wtrans<<<(256 * 512 + 255) / 256, 256, 0, stream>>>(W_n2, Wn2T, 512, 256, 512);
  wtrans<<<(256 * 256 + 255) / 256, 256, 0, stream>>>(W_f2, Wf2T, 256, 256, 256);
  build_wt<<<(512 * 16 + 255) / 256, 256, 0, stream>>>(W_e1, b_e1, Wt);
  cvt_bf<<<(NN * 256 + 255) / 256, 256, 0, stream>>>(h, hbf, NN * 256);

  // ---- CSR build ----
  edge_geom<<<(EE + 255) / 256, 256, 0, stream>>>(pos, rowp, colp, dist, icnt);
  scan_ptr<<<1, 1024, 0, stream>>>(icnt, ptr);
  copy_head<<<(NN + 255) / 256, 256, 0, stream>>>(ptr, head, cntf);
  fill_perm<<<(EE + 255) / 256, 256, 0, stream>>>(rowp, head, perm);
  chunk_meta<<<(nch + 255) / 256, 256, 0, stream>>>(ptr, meta, CN, nch, capE);

  // ---- P1 = h@We1[0:256], P2 = h@We1[256:512] ----
  dim3 gp(NP / 128, 4);
  gemm128<7, 0><<<gp, 256, 0, stream>>>(hbf, We1Ta, nullptr, P1, NN, 512, 256,
                                        nullptr, nullptr, nullptr, nullptr, 0.f);
  gemm128<7, 0><<<gp, 256, 0, stream>>>(hbf, We1Tb, nullptr, P2, NN, 512, 256,
                                        nullptr, nullptr, nullptr, nullptr, 0.f);

  // ---- phase A: fused edge pipeline (BM=64) ----
  for (int c = 0; c < nch; c++) {
    int nlo = c * CN;
    int cn = NN - nlo; if (cn > CN) cn = CN;
    edge_fused<<<capE / 64, 256, 0, stream>>>(
        P1, P2, dist, eattr, Wt, g_e, be_ln, b_e2, b_c1, W_a, b_a, W_c2,
        We2f, Wc1f, rowp, colp, perm, meta, c, mBuf, att, cw);
    node_agg<<<(cn + 3) / 4, 256, 0, stream>>>(mBuf, att, cw, pos, colp, perm, ptr,
                                               meta, c, aggbf, cagg, nlo, cn);
  }

  // ---- phase B: node pipeline ----
  gemm128<0, 2><<<gp, 256, 0, stream>>>(nullptr, Wn1T, b_n1, t2, NN, 512, 512,
                                        hbf, aggbf, nullptr, nullptr, 0.f);
  ln_512<<<NN, 128, 0, stream>>>(t2, g_n, bn_ln, NN);
  dim3 g5(NP / 128, 2);
  gemm128<1, 0><<<g5, 256, 0, stream>>>(t2, Wn2T, b_n2, hupd, NN, 256, 512,
                                        nullptr, nullptr, nullptr, nullptr, 0.f);
  hmid_ln<<<NN, 64, 0, stream>>>(h, hupd, g_o, bo_ln, outp);

  // ---- phase C: coords + feedback ----
  posnew_k<<<(NN * 3 + 255) / 256, 256, 0, stream>>>(pos, cagg, out_pos);
  dnn_k<<<(EE + 255) / 256, 256, 0, stream>>>(out_pos, rowp, colp, perm, dist);
  edge_fb2<<<(NN + 3) / 4, 256, 0, stream>>>(dist, ptr, W_f1, b_f1, Sbf);
  gemm128<2, 0><<<g5, 256, 0, stream>>>(Sbf, Wf2T, nullptr, outp, NN, 256, 256,
                                        nullptr, nullptr, cntf, b_f2, 0.1f);
}